// Round 6
// baseline (225.464 us; speedup 1.0000x reference)
//
#include <hip/hip_runtime.h>

typedef unsigned short u16;
typedef unsigned int u32;
typedef __bf16 bf16x8 __attribute__((ext_vector_type(8)));
typedef float f32x4 __attribute__((ext_vector_type(4)));

#define MTOT 8192
#define DM 1024
#define DI 256
#define TT 2048

#define AS1 __attribute__((address_space(1)))
#define AS3 __attribute__((address_space(3)))

__device__ __forceinline__ u16 f2bf(float f) {
    u32 u = __float_as_uint(f);
    return (u16)((u + 0x7fffu + ((u >> 16) & 1u)) >> 16);
}
__device__ __forceinline__ float b2f(u16 b) {
    return __uint_as_float((u32)b << 16);
}

// ================= prep: X cvt + wv cvt + 5 weight transposes in ONE launch =================
__device__ __forceinline__ void transpose_tile(const float* __restrict__ in,
                                               u16* __restrict__ out, int K, int N,
                                               int bx, int by) {
    __shared__ float t[32][33];
    int n0 = bx * 32, k0 = by * 32;
    int tx = threadIdx.x & 31, ty = threadIdx.x >> 5;
    #pragma unroll
    for (int i = ty; i < 32; i += 8) t[i][tx] = in[(long)(k0 + i) * N + n0 + tx];
    __syncthreads();
    #pragma unroll
    for (int i = ty; i < 32; i += 8) out[(long)(n0 + i) * K + k0 + tx] = f2bf(t[tx][i]);
}

__device__ __forceinline__ void cvt_range(const float* __restrict__ in,
                                          u16* __restrict__ out, long n4, int b, int nb) {
    long i = (long)b * 256 + threadIdx.x;
    long stride = (long)nb * 256;
    for (; i < n4; i += stride) {
        float4 v = reinterpret_cast<const float4*>(in)[i];
        union { u16 u[4]; uint2 p; } o;
        o.u[0] = f2bf(v.x); o.u[1] = f2bf(v.y); o.u[2] = f2bf(v.z); o.u[3] = f2bf(v.w);
        reinterpret_cast<uint2*>(out)[i] = o.p;
    }
}

__global__ __launch_bounds__(256) void prep_kernel(
    const float* __restrict__ x, u16* __restrict__ Xb,
    const float* __restrict__ wq, const float* __restrict__ wk, u16* __restrict__ Wqk_t,
    const float* __restrict__ wv, u16* __restrict__ Wv_b,
    const float* __restrict__ wo, u16* __restrict__ Wo_t,
    const float* __restrict__ w1, u16* __restrict__ W1_t,
    const float* __restrict__ w2, u16* __restrict__ W2_t)
{
    int b = blockIdx.x;
    if (b < 1024) { cvt_range(x, Xb, (long)MTOT * DM / 4, b, 1024); return; }
    b -= 1024;
    if (b < 256)  { transpose_tile(wq, Wqk_t,              1024,  256, b & 7,  b >> 3); return; }
    b -= 256;
    if (b < 256)  { transpose_tile(wk, Wqk_t + 256 * 1024, 1024,  256, b & 7,  b >> 3); return; }
    b -= 256;
    if (b < 256)  { cvt_range(wv, Wv_b, (long)DM * DM / 4, b, 256); return; }
    b -= 256;
    if (b < 1024) { transpose_tile(wo, Wo_t,               1024, 1024, b & 31, b >> 5); return; }
    b -= 1024;
    if (b < 256)  { transpose_tile(w1, W1_t,               1024,  256, b & 7,  b >> 3); return; }
    b -= 256;
    transpose_tile(w2, W2_t, 256, 1024, b & 31, b >> 5);
}

// ------- row softmax over T=2048: read raw bf16 scores, write fp32 attn + bf16 in place -------
__global__ __launch_bounds__(256) void softmax_kernel(u16* __restrict__ Sb, float* __restrict__ attn) {
    long row = blockIdx.x;
    int tid = threadIdx.x;
    uint4 q = reinterpret_cast<uint4*>(Sb + row * (long)TT)[tid];
    u32 w4[4] = {q.x, q.y, q.z, q.w};
    float vv[8];
    #pragma unroll
    for (int j = 0; j < 4; ++j) {
        vv[2 * j]     = __uint_as_float(w4[j] << 16);
        vv[2 * j + 1] = __uint_as_float(w4[j] & 0xffff0000u);
    }
    float m = vv[0];
    #pragma unroll
    for (int j = 1; j < 8; ++j) m = fmaxf(m, vv[j]);
    #pragma unroll
    for (int off = 32; off; off >>= 1) m = fmaxf(m, __shfl_xor(m, off));
    __shared__ float redm[4], reds[4];
    if ((tid & 63) == 0) redm[tid >> 6] = m;
    __syncthreads();
    m = fmaxf(fmaxf(redm[0], redm[1]), fmaxf(redm[2], redm[3]));
    float s = 0.f;
    #pragma unroll
    for (int j = 0; j < 8; ++j) { vv[j] = __expf(vv[j] - m); s += vv[j]; }
    #pragma unroll
    for (int off = 32; off; off >>= 1) s += __shfl_xor(s, off);
    if ((tid & 63) == 0) reds[tid >> 6] = s;
    __syncthreads();
    s = reds[0] + reds[1] + reds[2] + reds[3];
    float inv = 1.0f / s;
    #pragma unroll
    for (int j = 0; j < 8; ++j) vv[j] *= inv;
    float* p = attn + row * (long)TT;
    reinterpret_cast<float4*>(p)[tid * 2]     = make_float4(vv[0], vv[1], vv[2], vv[3]);
    reinterpret_cast<float4*>(p)[tid * 2 + 1] = make_float4(vv[4], vv[5], vv[6], vv[7]);
    union { u16 u[8]; uint4 q; } pk;
    #pragma unroll
    for (int j = 0; j < 8; ++j) pk.u[j] = f2bf(vv[j]);
    reinterpret_cast<uint4*>(Sb + row * (long)TT)[tid] = pk.q;
}

// XCD-chunked bijective swizzle (all grids %8==0).
__device__ __forceinline__ int xcd_swizzle(int bid, int nb) {
    return (bid & 7) * (nb >> 3) + (bid >> 3);
}

// ================== m97-structure 128x128 GEMM (small shapes) ==================
// MODE: 0 = bf16 C * scale  1 = bf16 C^T  3 = bf16 relu(C+bias)
//       6 = bf16(C+bias+addend_b)  7 = fp32(C+bias+addend_b)
template<int MODE>
__device__ __forceinline__ void gemm_body(
    u16* As, u16* Bs,
    const u16* __restrict__ A, int lda,
    const u16* __restrict__ Bt, int ldb,
    u16* __restrict__ Cb, int ldcb,
    float* __restrict__ Cf, int ldcf,
    int K, float scale,
    const float* __restrict__ bias,
    const u16* __restrict__ addend_b, int ld_add,
    long tile_m, long tile_n)
{
    const int tid = threadIdx.x;
    const int w = tid >> 6;
    const int l = tid & 63;
    const int lane15 = l & 15;
    const int lhi = l >> 4;

    const int srow = w * 8 + (l >> 3);
    const int scol = (((l & 7) ^ (l >> 3)) << 4) >> 1;

    const u16* aptr = A + (tile_m + srow) * (long)lda + scol;
    const u16* bptr = Bt + (tile_n + srow) * (long)ldb + scol;

    f32x4 acc[4][4] = {};

    const int wr = (w >> 1) * 64;
    const int wc = (w & 1) * 64;

    for (int k0 = 0; k0 < K; k0 += 64) {
        #pragma unroll
        for (int i = 0; i < 4; ++i) {
            __builtin_amdgcn_global_load_lds(
                (const AS1 void*)(aptr + (long)i * 32 * lda + k0),
                (AS3 void*)((char*)As + i * 4096 + w * 1024), 16, 0, 0);
        }
        #pragma unroll
        for (int i = 0; i < 4; ++i) {
            __builtin_amdgcn_global_load_lds(
                (const AS1 void*)(bptr + (long)i * 32 * ldb + k0),
                (AS3 void*)((char*)Bs + i * 4096 + w * 1024), 16, 0, 0);
        }
        __syncthreads();
        #pragma unroll
        for (int kk = 0; kk < 2; ++kk) {
            bf16x8 af[4], bfr[4];
            const int kb = (kk * 32 + lhi * 8) * 2;
            #pragma unroll
            for (int m = 0; m < 4; ++m) {
                int r = wr + m * 16 + lane15;
                af[m] = *reinterpret_cast<const bf16x8*>(
                    (const char*)As + r * 128 + (kb ^ ((r & 7) << 4)));
            }
            #pragma unroll
            for (int n = 0; n < 4; ++n) {
                int r = wc + n * 16 + lane15;
                bfr[n] = *reinterpret_cast<const bf16x8*>(
                    (const char*)Bs + r * 128 + (kb ^ ((r & 7) << 4)));
            }
            #pragma unroll
            for (int m = 0; m < 4; ++m)
                #pragma unroll
                for (int n = 0; n < 4; ++n)
                    acc[m][n] = __builtin_amdgcn_mfma_f32_16x16x32_bf16(
                        af[m], bfr[n], acc[m][n], 0, 0, 0);
        }
        __syncthreads();
    }

    #pragma unroll
    for (int m = 0; m < 4; ++m) {
        #pragma unroll
        for (int n = 0; n < 4; ++n) {
            long grow0 = tile_m + wr + m * 16 + lhi * 4;
            long gcol  = tile_n + wc + n * 16 + lane15;
            #pragma unroll
            for (int r = 0; r < 4; ++r) {
                long grow = grow0 + r;
                float v = acc[m][n][r];
                if (MODE == 0) v *= scale;
                if (MODE == 3 || MODE == 6 || MODE == 7) v += bias[gcol];
                if (MODE == 6 || MODE == 7) v += b2f(addend_b[grow * (long)ld_add + gcol]);
                if (MODE == 3) v = fmaxf(v, 0.0f);
                if (MODE == 0 || MODE == 3 || MODE == 6) Cb[grow * (long)ldcb + gcol] = f2bf(v);
                if (MODE == 1) Cb[gcol * (long)ldcb + grow] = f2bf(v);
                if (MODE == 7) Cf[grow * (long)ldcf + gcol] = v;
            }
        }
    }
}

template<int MODE>
__global__ __launch_bounds__(256) void gemm_bt(
    const u16* __restrict__ A, long sA, int lda,
    const u16* __restrict__ Bt, long sB, int ldb,
    u16* __restrict__ Cb, long sCb, int ldcb,
    float* __restrict__ Cf, long sCf, int ldcf,
    int K, float scale,
    const float* __restrict__ bias,
    const u16* __restrict__ addend_b, long sAdd, int ld_add,
    int gx, int gy)
{
    __shared__ __attribute__((aligned(16))) u16 As[128 * 64];
    __shared__ __attribute__((aligned(16))) u16 Bs[128 * 64];

    int lid = xcd_swizzle(blockIdx.x, gridDim.x);
    int x = lid % gx;
    int t = lid / gx;
    int y = t % gy;
    int z = t / gy;

    gemm_body<MODE>(As, Bs,
                    A + (long)z * sA, lda, Bt + (long)z * sB, ldb,
                    Cb + (long)z * sCb, ldcb, Cf + (long)z * sCf, ldcf,
                    K, scale, bias,
                    addend_b ? addend_b + (long)z * sAdd : addend_b, ld_add,
                    (long)y * 128, (long)x * 128);
}

// ================== 256x256 / BK=64 / 8-wave / 8-phase GEMM (T2+T3+T4+T5) ==================
// 512 threads (8 waves, 2M x 4N). LDS 128 KB: 2 dbuf x {A,B} x 2 halves x [128][64] bf16.
// Per wave: 128x64 output = 8 m-frags x 4 n-frags (f32x4 each). Per phase: one quadrant
// (4m x 2n) x K=64 -> 16 MFMA, 12 ds_read_b128 preceding. Raw s_barrier (NO __syncthreads:
// that drains vmcnt). Stage bursts (8 global_load_lds) issued 3 phases before their
// vmcnt(0), so the drain is covered by ~3x16 MFMA. XOR-16B swizzle on staging source
// and ds_read (bank-conflict-free, proven in the 128^2 kernel).
template<int MODE>
__device__ __forceinline__ void gemm256_body(
    char* ldsb,
    const u16* __restrict__ A, int lda,
    const u16* __restrict__ Bt, int ldb,
    u16* __restrict__ Cb, int ldcb,
    float* __restrict__ Cf, int ldcf,
    int K, float scale,
    const float* __restrict__ bias,
    const u16* __restrict__ addend_b, int ld_add,
    long tile_m, long tile_n)
{
    const int tid = threadIdx.x;
    const int w = tid >> 6;        // wave 0..7
    const int l = tid & 63;
    const int wm = w >> 2;         // 0..1 (M)
    const int wn = w & 3;          // 0..3 (N)
    const int lane15 = l & 15;
    const int lhi = l >> 4;
    const int sw = (l & 7) << 4;   // ds_read swizzle byte XOR (r&7 == l&7 for all frags)

    // staging source base (row = w*8 + l>>3 within a 64-row load chunk, pre-swizzled col)
    const int srow = w * 8 + (l >> 3);
    const int scol = ((l & 7) ^ (l >> 3)) * 8;
    const u16* aS = A + (tile_m + srow) * (long)lda + scol;
    const u16* bS = Bt + (tile_n + srow) * (long)ldb + scol;

    // stage one K-tile (A 256x64 + B 256x64) into buffer bufi; 16 loads/thread? no: 8.
    auto STAGE = [&](int tile, int bufi) {
        long kof = (long)tile << 6;
        char* ab = ldsb + bufi * 65536;
        #pragma unroll
        for (int h = 0; h < 2; ++h)
            #pragma unroll
            for (int i = 0; i < 2; ++i) {
                __builtin_amdgcn_global_load_lds(
                    (const AS1 void*)(aS + (long)(h * 128 + i * 64) * lda + kof),
                    (AS3 void*)(ab + h * 16384 + i * 8192 + w * 1024), 16, 0, 0);
                __builtin_amdgcn_global_load_lds(
                    (const AS1 void*)(bS + (long)(h * 128 + i * 64) * ldb + kof),
                    (AS3 void*)(ab + 32768 + h * 16384 + i * 8192 + w * 1024), 16, 0, 0);
            }
    };

    f32x4 acc[8][4] = {};

    const int NT = K >> 6;
    // prologue: stage tiles 0 and 1; wait tile 0 (8 loads of tile 1 stay in flight)
    STAGE(0, 0);
    STAGE(1, 1);
    asm volatile("s_waitcnt vmcnt(8)" ::: "memory");
    __builtin_amdgcn_s_barrier();

    for (int u = 0; u < (NT >> 1); ++u) {
        #pragma unroll
        for (int half = 0; half < 2; ++half) {        // half 0: tile 2u (buf0); half 1: tile 2u+1 (buf1)
            const char* abuf = ldsb + half * 65536 + wm * 16384;
            const char* bbuf = ldsb + half * 65536 + 32768 + (wn >> 1) * 16384;
            #pragma unroll
            for (int q = 0; q < 4; ++q) {             // quadrant: mq = q&1 (4 m-frags), nq = q>>1 (2 n-frags)
                bf16x8 af[4][2], bfr[2][2];
                #pragma unroll
                for (int m = 0; m < 4; ++m) {
                    int r = (q & 1) * 64 + m * 16 + lane15;
                    #pragma unroll
                    for (int ks = 0; ks < 2; ++ks)
                        af[m][ks] = *reinterpret_cast<const bf16x8*>(
                            abuf + r * 128 + ((ks * 64 + lhi * 16) ^ sw));
                }
                #pragma unroll
                for (int n = 0; n < 2; ++n) {
                    int rb = (wn & 1) * 64 + ((q >> 1) * 2 + n) * 16 + lane15;
                    #pragma unroll
                    for (int ks = 0; ks < 2; ++ks)
                        bfr[n][ks] = *reinterpret_cast<const bf16x8*>(
                            bbuf + rb * 128 + ((ks * 64 + lhi * 16) ^ sw));
                }
                if (half == 0 && q == 0 && u > 0) STAGE(2 * u + 1, 1);
                if (half == 1 && q == 0 && 2 * u + 2 < NT) STAGE(2 * u + 2, 0);
                __builtin_amdgcn_s_barrier();
                __builtin_amdgcn_s_setprio(1);
                #pragma unroll
                for (int m = 0; m < 4; ++m)
                    #pragma unroll
                    for (int n = 0; n < 2; ++n)
                        #pragma unroll
                        for (int ks = 0; ks < 2; ++ks)
                            acc[(q & 1) * 4 + m][(q >> 1) * 2 + n] =
                                __builtin_amdgcn_mfma_f32_16x16x32_bf16(
                                    af[m][ks], bfr[n][ks],
                                    acc[(q & 1) * 4 + m][(q >> 1) * 2 + n], 0, 0, 0);
                __builtin_amdgcn_s_setprio(0);
                if (q == 3) asm volatile("s_waitcnt vmcnt(0)" ::: "memory");
                __builtin_amdgcn_s_barrier();
            }
        }
    }

    // epilogue
    #pragma unroll
    for (int mf = 0; mf < 8; ++mf) {
        #pragma unroll
        for (int nf = 0; nf < 4; ++nf) {
            long grow0 = tile_m + wm * 128 + mf * 16 + lhi * 4;
            long gcol  = tile_n + wn * 64 + nf * 16 + lane15;
            #pragma unroll
            for (int r = 0; r < 4; ++r) {
                long grow = grow0 + r;
                float v = acc[mf][nf][r];
                if (MODE == 0) v *= scale;
                if (MODE == 6) v += bias[gcol] + b2f(addend_b[grow * (long)ld_add + gcol]);
                if (MODE == 0 || MODE == 6) Cb[grow * (long)ldcb + gcol] = f2bf(v);
            }
        }
    }
}

template<int MODE>
__global__ __launch_bounds__(512) void gemm256_bt(
    const u16* __restrict__ A, long sA, int lda,
    const u16* __restrict__ Bt, long sB, int ldb,
    u16* __restrict__ Cb, long sCb, int ldcb,
    int K, float scale,
    const float* __restrict__ bias,
    const u16* __restrict__ addend_b, long sAdd, int ld_add,
    int gx, int tpz)
{
    __shared__ __attribute__((aligned(16))) u16 lds[65536];
    int lid = xcd_swizzle(blockIdx.x, gridDim.x);
    int z = lid / tpz, rem = lid % tpz;
    int x = rem % gx, y = rem / gx;
    gemm256_body<MODE>((char*)lds,
                       A + (long)z * sA, lda, Bt + (long)z * sB, ldb,
                       Cb + (long)z * sCb, ldcb, (float*)nullptr, 0,
                       K, scale, bias,
                       addend_b ? addend_b + (long)z * sAdd : addend_b, ld_add,
                       (long)y * 256, (long)x * 256);
}

// Merged QKV on the 256^2 kernel: lids [0,64): QK = Xb @ Wqk_t^T (8192x512, 2x32 tiles);
// lids [64,192): VW^T = Wvo^T @ X^T (1024x8192, 32x4 tiles, x-slow for per-XCD B locality).
__global__ __launch_bounds__(512) void gemm256_qkv(
    const u16* __restrict__ Xb, const u16* __restrict__ Wqk_t, u16* __restrict__ QKb,
    const u16* __restrict__ Wvo_t, u16* __restrict__ VWt)
{
    __shared__ __attribute__((aligned(16))) u16 lds[65536];
    int lid = xcd_swizzle(blockIdx.x, gridDim.x);
    if (lid < 64) {
        int x = lid & 1, y = lid >> 1;
        gemm256_body<0>((char*)lds, Xb, 1024, Wqk_t, 1024, QKb, 512,
                        (float*)nullptr, 0, 1024, 1.0f,
                        (const float*)nullptr, (const u16*)nullptr, 0,
                        (long)y * 256, (long)x * 256);
    } else {
        int l2 = lid - 64;
        int x = l2 >> 2, y = l2 & 3;
        gemm256_body<0>((char*)lds, Wvo_t, 1024, Xb, 1024, VWt, 8192,
                        (float*)nullptr, 0, 1024, 1.0f,
                        (const float*)nullptr, (const u16*)nullptr, 0,
                        (long)y * 256, (long)x * 256);
    }
}

extern "C" void kernel_launch(void* const* d_in, const int* in_sizes, int n_in,
                              void* d_out, int out_size, void* d_ws, size_t ws_size,
                              hipStream_t stream)
{
    const float* x  = (const float*)d_in[0];
    const float* wq = (const float*)d_in[1];
    const float* wk = (const float*)d_in[2];
    const float* wv = (const float*)d_in[3];
    const float* wo = (const float*)d_in[4];
    const float* bo = (const float*)d_in[5];
    const float* w1 = (const float*)d_in[6];
    const float* b1 = (const float*)d_in[7];
    const float* w2 = (const float*)d_in[8];
    const float* b2 = (const float*)d_in[9];

    float* out_f  = (float*)d_out;
    float* attn_f = out_f + (long)MTOT * DM;

    char* ws = (char*)d_ws;
    u16* Xb    = (u16*)(ws + 0);            // 16 MB bf16 X (also residual addend)
    u16* Wqk_t = (u16*)(ws + 16777216);     // 1 MB  (512,1024)
    u16* Wv_b  = (u16*)(ws + 17825792);     // 2 MB  wv bf16
    u16* Wo_t  = (u16*)(ws + 19922944);     // 2 MB  wo^T
    u16* W1_t  = (u16*)(ws + 22020096);     // 0.5 MB
    u16* W2_t  = (u16*)(ws + 22544384);     // 0.5 MB
    u16* Wvo_t = (u16*)(ws + 23068672);     // 2 MB  (Wv@Wo)^T
    u16* QKb   = (u16*)(ws + 25165824);     // 8 MB  (8192,512) (reused as h)
    u16* VWt   = (u16*)(ws + 33554432);     // 16 MB (1024,8192)
    u16* attnb = (u16*)(ws + 50331648);     // 32 MB raw scores -> attn bf16
    u16* res_b = (u16*)(ws + 83886080);     // 16 MB residual bf16
    u16* hb    = QKb;

    dim3 blk(256), blk5(512);

    // 1. prep
    prep_kernel<<<dim3(3328), blk, 0, stream>>>(x, Xb, wq, wk, Wqk_t, wv, Wv_b,
                                                wo, Wo_t, w1, W1_t, w2, W2_t);
    // 2. Wvo^T = (Wv @ Wo)^T (m97, mode 1)
    gemm_bt<1><<<dim3(64), blk, 0, stream>>>(
        Wv_b, 0L, 1024, Wo_t, 0L, 1024, Wvo_t, 0L, 1024,
        (float*)nullptr, 0L, 0, 1024, 1.0f, (const float*)nullptr,
        (const u16*)nullptr, 0L, 0, 8, 8);
    // 3. merged QK + VW^T (256^2 8-phase)
    gemm256_qkv<<<dim3(192), blk5, 0, stream>>>(Xb, Wqk_t, QKb, Wvo_t, VWt);
    // 4. raw scores (bf16) = Q @ K^T * 1/16 (256^2 8-phase, per batch)
    gemm256_bt<0><<<dim3(256), blk5, 0, stream>>>(
        QKb, (long)2048 * 512, 512, QKb + 256, (long)2048 * 512, 512,
        attnb, (long)2048 * 2048, 2048,
        256, 0.0625f, (const float*)nullptr, (const u16*)nullptr, 0L, 0, 8, 64);
    // 5. softmax
    softmax_kernel<<<dim3(8192), blk, 0, stream>>>(attnb, attn_f);
    // 6. residual(bf16) = bf16(attn @ VW + bo + Xb) (256^2 8-phase, per batch)
    gemm256_bt<6><<<dim3(128), blk5, 0, stream>>>(
        attnb, (long)2048 * 2048, 2048, VWt, 2048L, 8192,
        res_b, (long)2048 * 1024, 1024,
        2048, 1.0f, bo, Xb, (long)2048 * 1024, 1024, 4, 32);
    // 7. h = relu(residual @ w1 + b1) (m97)
    gemm_bt<3><<<dim3(128), blk, 0, stream>>>(
        res_b, 0L, 1024, W1_t, 0L, 1024, hb, 0L, 256,
        (float*)nullptr, 0L, 0, 1024, 1.0f, b1, (const u16*)nullptr, 0L, 0, 2, 64);
    // 8. out = residual + h @ w2 + b2 (m97, fp32 out)
    gemm_bt<7><<<dim3(512), blk, 0, stream>>>(
        hb, 0L, 256, W2_t, 0L, 256, (u16*)nullptr, 0L, 0,
        out_f, 0L, 1024, 256, 1.0f, b2, res_b, 0L, 1024, 8, 64);
}

// Round 7
// 191.563 us; speedup vs baseline: 1.1770x; 1.1770x over previous
//
#include <hip/hip_runtime.h>

typedef unsigned short u16;
typedef unsigned int u32;
typedef __bf16 bf16x8 __attribute__((ext_vector_type(8)));
typedef float f32x4 __attribute__((ext_vector_type(4)));

#define MTOT 8192
#define DM 1024
#define DI 256
#define TT 2048

#define AS1 __attribute__((address_space(1)))
#define AS3 __attribute__((address_space(3)))

__device__ __forceinline__ u16 f2bf(float f) {
    u32 u = __float_as_uint(f);
    return (u16)((u + 0x7fffu + ((u >> 16) & 1u)) >> 16);
}
__device__ __forceinline__ float b2f(u16 b) {
    return __uint_as_float((u32)b << 16);
}

// ================= prep: X cvt + wv cvt + 5 weight transposes in ONE launch =================
__device__ __forceinline__ void transpose_tile(const float* __restrict__ in,
                                               u16* __restrict__ out, int K, int N,
                                               int bx, int by) {
    __shared__ float t[32][33];
    int n0 = bx * 32, k0 = by * 32;
    int tx = threadIdx.x & 31, ty = threadIdx.x >> 5;
    #pragma unroll
    for (int i = ty; i < 32; i += 8) t[i][tx] = in[(long)(k0 + i) * N + n0 + tx];
    __syncthreads();
    #pragma unroll
    for (int i = ty; i < 32; i += 8) out[(long)(n0 + i) * K + k0 + tx] = f2bf(t[tx][i]);
}

__device__ __forceinline__ void cvt_range(const float* __restrict__ in,
                                          u16* __restrict__ out, long n4, int b, int nb) {
    long i = (long)b * 256 + threadIdx.x;
    long stride = (long)nb * 256;
    for (; i < n4; i += stride) {
        float4 v = reinterpret_cast<const float4*>(in)[i];
        union { u16 u[4]; uint2 p; } o;
        o.u[0] = f2bf(v.x); o.u[1] = f2bf(v.y); o.u[2] = f2bf(v.z); o.u[3] = f2bf(v.w);
        reinterpret_cast<uint2*>(out)[i] = o.p;
    }
}

__global__ __launch_bounds__(256) void prep_kernel(
    const float* __restrict__ x, u16* __restrict__ Xb,
    const float* __restrict__ wq, const float* __restrict__ wk, u16* __restrict__ Wqk_t,
    const float* __restrict__ wv, u16* __restrict__ Wv_b,
    const float* __restrict__ wo, u16* __restrict__ Wo_t,
    const float* __restrict__ w1, u16* __restrict__ W1_t,
    const float* __restrict__ w2, u16* __restrict__ W2_t)
{
    int b = blockIdx.x;
    if (b < 1024) { cvt_range(x, Xb, (long)MTOT * DM / 4, b, 1024); return; }
    b -= 1024;
    if (b < 256)  { transpose_tile(wq, Wqk_t,              1024,  256, b & 7,  b >> 3); return; }
    b -= 256;
    if (b < 256)  { transpose_tile(wk, Wqk_t + 256 * 1024, 1024,  256, b & 7,  b >> 3); return; }
    b -= 256;
    if (b < 256)  { cvt_range(wv, Wv_b, (long)DM * DM / 4, b, 256); return; }
    b -= 256;
    if (b < 1024) { transpose_tile(wo, Wo_t,               1024, 1024, b & 31, b >> 5); return; }
    b -= 1024;
    if (b < 256)  { transpose_tile(w1, W1_t,               1024,  256, b & 7,  b >> 3); return; }
    b -= 256;
    transpose_tile(w2, W2_t, 256, 1024, b & 31, b >> 5);
}

// ------- row softmax over T=2048: read raw bf16 scores, write fp32 attn + bf16 in place -------
__global__ __launch_bounds__(256) void softmax_kernel(u16* __restrict__ Sb, float* __restrict__ attn) {
    long row = blockIdx.x;
    int tid = threadIdx.x;
    uint4 q = reinterpret_cast<uint4*>(Sb + row * (long)TT)[tid];
    u32 w4[4] = {q.x, q.y, q.z, q.w};
    float vv[8];
    #pragma unroll
    for (int j = 0; j < 4; ++j) {
        vv[2 * j]     = __uint_as_float(w4[j] << 16);
        vv[2 * j + 1] = __uint_as_float(w4[j] & 0xffff0000u);
    }
    float m = vv[0];
    #pragma unroll
    for (int j = 1; j < 8; ++j) m = fmaxf(m, vv[j]);
    #pragma unroll
    for (int off = 32; off; off >>= 1) m = fmaxf(m, __shfl_xor(m, off));
    __shared__ float redm[4], reds[4];
    if ((tid & 63) == 0) redm[tid >> 6] = m;
    __syncthreads();
    m = fmaxf(fmaxf(redm[0], redm[1]), fmaxf(redm[2], redm[3]));
    float s = 0.f;
    #pragma unroll
    for (int j = 0; j < 8; ++j) { vv[j] = __expf(vv[j] - m); s += vv[j]; }
    #pragma unroll
    for (int off = 32; off; off >>= 1) s += __shfl_xor(s, off);
    if ((tid & 63) == 0) reds[tid >> 6] = s;
    __syncthreads();
    s = reds[0] + reds[1] + reds[2] + reds[3];
    float inv = 1.0f / s;
    #pragma unroll
    for (int j = 0; j < 8; ++j) vv[j] *= inv;
    float* p = attn + row * (long)TT;
    reinterpret_cast<float4*>(p)[tid * 2]     = make_float4(vv[0], vv[1], vv[2], vv[3]);
    reinterpret_cast<float4*>(p)[tid * 2 + 1] = make_float4(vv[4], vv[5], vv[6], vv[7]);
    union { u16 u[8]; uint4 q; } pk;
    #pragma unroll
    for (int j = 0; j < 8; ++j) pk.u[j] = f2bf(vv[j]);
    reinterpret_cast<uint4*>(Sb + row * (long)TT)[tid] = pk.q;
}

// XCD-chunked bijective swizzle (all grids %8==0).
__device__ __forceinline__ int xcd_swizzle(int bid, int nb) {
    return (bid & 7) * (nb >> 3) + (bid >> 3);
}

// ================== m97-structure 128x128 GEMM (small shapes) ==================
// MODE: 1 = bf16 C^T  3 = bf16 relu(C+bias)  7 = fp32(C+bias+addend_b)
template<int MODE>
__device__ __forceinline__ void gemm_body(
    u16* As, u16* Bs,
    const u16* __restrict__ A, int lda,
    const u16* __restrict__ Bt, int ldb,
    u16* __restrict__ Cb, int ldcb,
    float* __restrict__ Cf, int ldcf,
    int K, float scale,
    const float* __restrict__ bias,
    const u16* __restrict__ addend_b, int ld_add,
    long tile_m, long tile_n)
{
    const int tid = threadIdx.x;
    const int w = tid >> 6;
    const int l = tid & 63;
    const int lane15 = l & 15;
    const int lhi = l >> 4;

    const int srow = w * 8 + (l >> 3);
    const int scol = (((l & 7) ^ (l >> 3)) << 4) >> 1;

    const u16* aptr = A + (tile_m + srow) * (long)lda + scol;
    const u16* bptr = Bt + (tile_n + srow) * (long)ldb + scol;

    f32x4 acc[4][4] = {};

    const int wr = (w >> 1) * 64;
    const int wc = (w & 1) * 64;

    for (int k0 = 0; k0 < K; k0 += 64) {
        #pragma unroll
        for (int i = 0; i < 4; ++i) {
            __builtin_amdgcn_global_load_lds(
                (const AS1 void*)(aptr + (long)i * 32 * lda + k0),
                (AS3 void*)((char*)As + i * 4096 + w * 1024), 16, 0, 0);
        }
        #pragma unroll
        for (int i = 0; i < 4; ++i) {
            __builtin_amdgcn_global_load_lds(
                (const AS1 void*)(bptr + (long)i * 32 * ldb + k0),
                (AS3 void*)((char*)Bs + i * 4096 + w * 1024), 16, 0, 0);
        }
        __syncthreads();
        #pragma unroll
        for (int kk = 0; kk < 2; ++kk) {
            bf16x8 af[4], bfr[4];
            const int kb = (kk * 32 + lhi * 8) * 2;
            #pragma unroll
            for (int m = 0; m < 4; ++m) {
                int r = wr + m * 16 + lane15;
                af[m] = *reinterpret_cast<const bf16x8*>(
                    (const char*)As + r * 128 + (kb ^ ((r & 7) << 4)));
            }
            #pragma unroll
            for (int n = 0; n < 4; ++n) {
                int r = wc + n * 16 + lane15;
                bfr[n] = *reinterpret_cast<const bf16x8*>(
                    (const char*)Bs + r * 128 + (kb ^ ((r & 7) << 4)));
            }
            #pragma unroll
            for (int m = 0; m < 4; ++m)
                #pragma unroll
                for (int n = 0; n < 4; ++n)
                    acc[m][n] = __builtin_amdgcn_mfma_f32_16x16x32_bf16(
                        af[m], bfr[n], acc[m][n], 0, 0, 0);
        }
        __syncthreads();
    }

    #pragma unroll
    for (int m = 0; m < 4; ++m) {
        #pragma unroll
        for (int n = 0; n < 4; ++n) {
            long grow0 = tile_m + wr + m * 16 + lhi * 4;
            long gcol  = tile_n + wc + n * 16 + lane15;
            #pragma unroll
            for (int r = 0; r < 4; ++r) {
                long grow = grow0 + r;
                float v = acc[m][n][r];
                if (MODE == 3 || MODE == 7) v += bias[gcol];
                if (MODE == 7) v += b2f(addend_b[grow * (long)ld_add + gcol]);
                if (MODE == 3) v = fmaxf(v, 0.0f);
                if (MODE == 3) Cb[grow * (long)ldcb + gcol] = f2bf(v);
                if (MODE == 1) Cb[gcol * (long)ldcb + grow] = f2bf(v);
                if (MODE == 7) Cf[grow * (long)ldcf + gcol] = v;
            }
        }
    }
}

template<int MODE>
__global__ __launch_bounds__(256) void gemm_bt(
    const u16* __restrict__ A, long sA, int lda,
    const u16* __restrict__ Bt, long sB, int ldb,
    u16* __restrict__ Cb, long sCb, int ldcb,
    float* __restrict__ Cf, long sCf, int ldcf,
    int K, float scale,
    const float* __restrict__ bias,
    const u16* __restrict__ addend_b, long sAdd, int ld_add,
    int gx, int gy)
{
    __shared__ __attribute__((aligned(16))) u16 As[128 * 64];
    __shared__ __attribute__((aligned(16))) u16 Bs[128 * 64];

    int lid = xcd_swizzle(blockIdx.x, gridDim.x);
    int x = lid % gx;
    int t = lid / gx;
    int y = t % gy;
    int z = t / gy;

    gemm_body<MODE>(As, Bs,
                    A + (long)z * sA, lda, Bt + (long)z * sB, ldb,
                    Cb + (long)z * sCb, ldcb, Cf + (long)z * sCf, ldcf,
                    K, scale, bias,
                    addend_b ? addend_b + (long)z * sAdd : addend_b, ld_add,
                    (long)y * 128, (long)x * 128);
}

// ====== 256x128 / BK=64 / 8-wave / 3-buffer deep-pipeline GEMM (T2+T3+T4+T5) ======
// 512 threads = 8 waves (4M x 2N), per-wave output 64x64 (4x4 f32x4 frags).
// LDS: 3 K-tile buffers x (A 256x64 + B 128x64) bf16 = 3 x 48KB = 144KB.
// Pipeline: STAGE(t+2) issued during tile t (3 loads per phase) into buffer freed
// at t-1; end-of-tile wait is vmcnt(6) (= in-flight loads of t+2) so tile t+1's
// loads get ~1.5 K-tiles of MFMA cover and are NEVER drained (T4). Raw s_barrier
// (no __syncthreads -> no vmcnt drain). XOR-16B swizzle on stage source + ds_read.
// MODE: 0 = bf16 C*scale   1 = bf16 C^T   6 = bf16(C + bias + bf16 addend)
template<int MODE>
__device__ __forceinline__ void g256_body(
    char* ldsb,
    const u16* __restrict__ A, int lda,
    const u16* __restrict__ Bt, int ldb,
    u16* __restrict__ Cb, int ldcb,
    int K, float scale,
    const float* __restrict__ bias,
    const u16* __restrict__ addend_b, int ld_add,
    long tile_m, long tile_n)
{
    const int tid = threadIdx.x;
    const int w = tid >> 6;
    const int l = tid & 63;
    const int wm = w >> 1;          // 0..3 (M quarter)
    const int wn = w & 1;           // 0..1 (N half)
    const int lane15 = l & 15;
    const int lhi = l >> 4;
    const int sw = (l & 7) << 4;    // ds_read XOR (row&7 == l&7 for all fragments)

    const int srow = w * 8 + (l >> 3);
    const int scol = ((l & 7) ^ (l >> 3)) * 8;
    const u16* aS = A + (tile_m + srow) * (long)lda + scol;
    const u16* bS = Bt + (tile_n + srow) * (long)ldb + scol;

    // stage half of K-tile t (phase ph): 2 A-loads + 1 B-load (each 8KB = 64 rows)
    auto STAGE_P = [&](int t, int ph) {
        long kof = (long)t << 6;
        char* buf = ldsb + (t % 3) * 49152;
        __builtin_amdgcn_global_load_lds(
            (const AS1 void*)(aS + (long)(ph * 128) * lda + kof),
            (AS3 void*)(buf + ph * 16384 + w * 1024), 16, 0, 0);
        __builtin_amdgcn_global_load_lds(
            (const AS1 void*)(aS + (long)(ph * 128 + 64) * lda + kof),
            (AS3 void*)(buf + ph * 16384 + 8192 + w * 1024), 16, 0, 0);
        __builtin_amdgcn_global_load_lds(
            (const AS1 void*)(bS + (long)(ph * 64) * ldb + kof),
            (AS3 void*)(buf + 32768 + ph * 8192 + w * 1024), 16, 0, 0);
    };

    f32x4 acc[4][4] = {};
    const int NT = K >> 6;

    // prologue: stage tiles 0,1 (12 loads); wait tile 0 (6 newest = tile 1 stay in flight)
    STAGE_P(0, 0); STAGE_P(0, 1);
    STAGE_P(1, 0); STAGE_P(1, 1);
    asm volatile("s_waitcnt vmcnt(6)" ::: "memory");
    __builtin_amdgcn_s_barrier();

    for (int t = 0; t < NT; ++t) {
        const char* ab = ldsb + (t % 3) * 49152;
        const char* bb = ab + 32768;
        const bool st = (t + 2) < NT;

        // ---- phase 0 (ks = 0) ----
        bf16x8 a0[4], b0[4];
        #pragma unroll
        for (int m = 0; m < 4; ++m)
            a0[m] = *reinterpret_cast<const bf16x8*>(
                ab + (wm * 64 + m * 16 + lane15) * 128 + ((lhi * 16) ^ sw));
        #pragma unroll
        for (int n = 0; n < 4; ++n)
            b0[n] = *reinterpret_cast<const bf16x8*>(
                bb + (wn * 64 + n * 16 + lane15) * 128 + ((lhi * 16) ^ sw));
        if (st) STAGE_P(t + 2, 0);
        __builtin_amdgcn_s_barrier();
        __builtin_amdgcn_s_setprio(1);
        #pragma unroll
        for (int m = 0; m < 4; ++m)
            #pragma unroll
            for (int n = 0; n < 4; ++n)
                acc[m][n] = __builtin_amdgcn_mfma_f32_16x16x32_bf16(
                    a0[m], b0[n], acc[m][n], 0, 0, 0);
        __builtin_amdgcn_s_setprio(0);
        __builtin_amdgcn_s_barrier();

        // ---- phase 1 (ks = 1) ----
        bf16x8 a1[4], b1[4];
        #pragma unroll
        for (int m = 0; m < 4; ++m)
            a1[m] = *reinterpret_cast<const bf16x8*>(
                ab + (wm * 64 + m * 16 + lane15) * 128 + ((64 + lhi * 16) ^ sw));
        #pragma unroll
        for (int n = 0; n < 4; ++n)
            b1[n] = *reinterpret_cast<const bf16x8*>(
                bb + (wn * 64 + n * 16 + lane15) * 128 + ((64 + lhi * 16) ^ sw));
        if (st) STAGE_P(t + 2, 1);
        __builtin_amdgcn_s_barrier();
        __builtin_amdgcn_s_setprio(1);
        #pragma unroll
        for (int m = 0; m < 4; ++m)
            #pragma unroll
            for (int n = 0; n < 4; ++n)
                acc[m][n] = __builtin_amdgcn_mfma_f32_16x16x32_bf16(
                    a1[m], b1[n], acc[m][n], 0, 0, 0);
        __builtin_amdgcn_s_setprio(0);
        if (t < NT - 1) {
            if (st) asm volatile("s_waitcnt vmcnt(6)" ::: "memory");
            else    asm volatile("s_waitcnt vmcnt(0)" ::: "memory");
        }
        __builtin_amdgcn_s_barrier();
    }

    // epilogue
    #pragma unroll
    for (int mf = 0; mf < 4; ++mf) {
        #pragma unroll
        for (int nf = 0; nf < 4; ++nf) {
            long grow0 = tile_m + wm * 64 + mf * 16 + lhi * 4;
            long gcol  = tile_n + wn * 64 + nf * 16 + lane15;
            #pragma unroll
            for (int r = 0; r < 4; ++r) {
                long grow = grow0 + r;
                float v = acc[mf][nf][r];
                if (MODE == 0) v *= scale;
                if (MODE == 6) v += bias[gcol] + b2f(addend_b[grow * (long)ld_add + gcol]);
                if (MODE == 0 || MODE == 6) Cb[grow * (long)ldcb + gcol] = f2bf(v);
                if (MODE == 1) Cb[gcol * (long)ldcb + grow] = f2bf(v);
            }
        }
    }
}

template<int MODE>
__global__ __launch_bounds__(512) void g256_bt(
    const u16* __restrict__ A, long sA, int lda,
    const u16* __restrict__ Bt, long sB, int ldb,
    u16* __restrict__ Cb, long sCb, int ldcb,
    int K, float scale,
    const float* __restrict__ bias,
    const u16* __restrict__ addend_b, long sAdd, int ld_add,
    int gx, int tpz)
{
    __shared__ __attribute__((aligned(16))) char lds[147456];
    int lid = xcd_swizzle(blockIdx.x, gridDim.x);
    int z = lid / tpz, rem = lid % tpz;
    int x = rem % gx, y = rem / gx;
    g256_body<MODE>(lds,
                    A + (long)z * sA, lda, Bt + (long)z * sB, ldb,
                    Cb + (long)z * sCb, ldcb,
                    K, scale, bias,
                    addend_b ? addend_b + (long)z * sAdd : addend_b, ld_add,
                    (long)y * 256, (long)x * 128);
}

// Merged QK + VW^T: lids [0,128): QK = Xb @ Wqk_t^T (8192x512, 32y x 4x tiles);
// lids [128,384): VW^T = (Xb @ Wvo_t^T)^T -> (1024,8192), 32y x 8x tiles, mode 1.
__global__ __launch_bounds__(512) void g256_qkvw(
    const u16* __restrict__ Xb, const u16* __restrict__ Wqk_t, u16* __restrict__ QKb,
    const u16* __restrict__ Wvo_t, u16* __restrict__ VWt)
{
    __shared__ __attribute__((aligned(16))) char lds[147456];
    int lid = xcd_swizzle(blockIdx.x, gridDim.x);
    if (lid < 128) {
        int x = lid & 3, y = lid >> 2;
        g256_body<0>(lds, Xb, 1024, Wqk_t, 1024, QKb, 512,
                     1024, 1.0f, (const float*)nullptr, (const u16*)nullptr, 0,
                     (long)y * 256, (long)x * 128);
    } else {
        int l2 = lid - 128;
        int x = l2 & 7, y = l2 >> 3;
        g256_body<1>(lds, Xb, 1024, Wvo_t, 1024, VWt, 8192,
                     1024, 1.0f, (const float*)nullptr, (const u16*)nullptr, 0,
                     (long)y * 256, (long)x * 128);
    }
}

extern "C" void kernel_launch(void* const* d_in, const int* in_sizes, int n_in,
                              void* d_out, int out_size, void* d_ws, size_t ws_size,
                              hipStream_t stream)
{
    const float* x  = (const float*)d_in[0];
    const float* wq = (const float*)d_in[1];
    const float* wk = (const float*)d_in[2];
    const float* wv = (const float*)d_in[3];
    const float* wo = (const float*)d_in[4];
    const float* bo = (const float*)d_in[5];
    const float* w1 = (const float*)d_in[6];
    const float* b1 = (const float*)d_in[7];
    const float* w2 = (const float*)d_in[8];
    const float* b2 = (const float*)d_in[9];

    float* out_f  = (float*)d_out;
    float* attn_f = out_f + (long)MTOT * DM;

    char* ws = (char*)d_ws;
    u16* Xb    = (u16*)(ws + 0);            // 16 MB bf16 X (also residual addend)
    u16* Wqk_t = (u16*)(ws + 16777216);     // 1 MB  (512,1024)
    u16* Wv_b  = (u16*)(ws + 17825792);     // 2 MB  wv bf16
    u16* Wo_t  = (u16*)(ws + 19922944);     // 2 MB  wo^T
    u16* W1_t  = (u16*)(ws + 22020096);     // 0.5 MB
    u16* W2_t  = (u16*)(ws + 22544384);     // 0.5 MB
    u16* Wvo_t = (u16*)(ws + 23068672);     // 2 MB  (Wv@Wo)^T
    u16* QKb   = (u16*)(ws + 25165824);     // 8 MB  (8192,512) (reused as h)
    u16* VWt   = (u16*)(ws + 33554432);     // 16 MB (1024,8192)
    u16* attnb = (u16*)(ws + 50331648);     // 32 MB raw scores -> attn bf16
    u16* res_b = (u16*)(ws + 83886080);     // 16 MB residual bf16
    u16* hb    = QKb;

    dim3 blk(256), blk5(512);

    // 1. prep
    prep_kernel<<<dim3(3328), blk, 0, stream>>>(x, Xb, wq, wk, Wqk_t, wv, Wv_b,
                                                wo, Wo_t, w1, W1_t, w2, W2_t);
    // 2. Wvo^T = (Wv @ Wo)^T (m97, mode 1)
    gemm_bt<1><<<dim3(64), blk, 0, stream>>>(
        Wv_b, 0L, 1024, Wo_t, 0L, 1024, Wvo_t, 0L, 1024,
        (float*)nullptr, 0L, 0, 1024, 1.0f, (const float*)nullptr,
        (const u16*)nullptr, 0L, 0, 8, 8);
    // 3. merged QK + VW^T (256x128 pipelined)
    g256_qkvw<<<dim3(384), blk5, 0, stream>>>(Xb, Wqk_t, QKb, Wvo_t, VWt);
    // 4. raw scores (bf16) = Q @ K^T * 1/16 (per batch)
    g256_bt<0><<<dim3(512), blk5, 0, stream>>>(
        QKb, (long)2048 * 512, 512, QKb + 256, (long)2048 * 512, 512,
        attnb, (long)2048 * 2048, 2048,
        256, 0.0625f, (const float*)nullptr, (const u16*)nullptr, 0L, 0, 16, 128);
    // 5. softmax
    softmax_kernel<<<dim3(8192), blk, 0, stream>>>(attnb, attn_f);
    // 6. residual(bf16) = bf16(attn @ VW + bo + Xb) (per batch)
    g256_bt<6><<<dim3(256), blk5, 0, stream>>>(
        attnb, (long)2048 * 2048, 2048, VWt, 2048L, 8192,
        res_b, (long)2048 * 1024, 1024,
        2048, 1.0f, bo, Xb, (long)2048 * 1024, 1024, 8, 64);
    // 7. h = relu(residual @ w1 + b1) (m97)
    gemm_bt<3><<<dim3(128), blk, 0, stream>>>(
        res_b, 0L, 1024, W1_t, 0L, 1024, hb, 0L, 256,
        (float*)nullptr, 0L, 0, 1024, 1.0f, b1, (const u16*)nullptr, 0L, 0, 2, 64);
    // 8. out = residual + h @ w2 + b2 (m97, fp32 out)
    gemm_bt<7><<<dim3(512), blk, 0, stream>>>(
        hb, 0L, 256, W2_t, 0L, 256, (u16*)nullptr, 0L, 0,
        out_f, 0L, 1024, 256, 1.0f, b2, res_b, 0L, 1024, 8, 64);
}